// Round 2
// baseline (9843.787 us; speedup 1.0000x reference)
//
#include <hip/hip_runtime.h>
#include <stdint.h>

// ---------------- problem constants ----------------
#define NU 50000
#define NI 30000
#define NN 80000   // NU+NI
#define EK 64
#define HK 32
#define KV 4096
#define KT 384
#define NNZ_A 2000000
#define NNZ_R 1000000

// JAX >= 0.4.36 defaults jax_threefry_partitionable=True. Flip to 0 if the
// bench shows large error concentrated on the gumbel-dependent outputs.
#define JAX_PARTITIONABLE 1

// ---------------- threefry2x32 (20 rounds) ----------------
__host__ __device__ static inline void tf2x32(uint32_t k0, uint32_t k1,
                                              uint32_t x0, uint32_t x1,
                                              uint32_t& o0, uint32_t& o1) {
  uint32_t ks2 = k0 ^ k1 ^ 0x1BD11BDAu;
#define ROTL(x,d) (((x)<<(d))|((x)>>(32-(d))))
#define RND(r) { x0 += x1; x1 = ROTL(x1,r); x1 ^= x0; }
  x0 += k0; x1 += k1;
  RND(13) RND(15) RND(26) RND(6)
  x0 += k1;  x1 += ks2 + 1u;
  RND(17) RND(29) RND(16) RND(24)
  x0 += ks2; x1 += k0 + 2u;
  RND(13) RND(15) RND(26) RND(6)
  x0 += k0;  x1 += k1 + 3u;
  RND(17) RND(29) RND(16) RND(24)
  x0 += k1;  x1 += ks2 + 4u;
  RND(13) RND(15) RND(26) RND(6)
  x0 += ks2; x1 += k0 + 5u;
  o0 = x0; o1 = x1;
#undef RND
#undef ROTL
}

// ---------------- CSR build ----------------
__global__ void k_hist(const int* __restrict__ rows, int n, int* __restrict__ cnt) {
  int g = blockIdx.x * blockDim.x + threadIdx.x;
  if (g < n) atomicAdd(&cnt[rows[g]], 1);
}

// single-block exclusive scan (1024 threads), writes ptr[0..n] and fill[0..n-1]=ptr
__global__ void k_exscan(const int* __restrict__ cnt, int* __restrict__ ptr,
                         int* __restrict__ fill, int n) {
  __shared__ int wsum[16];
  __shared__ int s_carry;
  int tid = threadIdx.x;
  int lane = tid & 63, w = tid >> 6;
  if (tid == 0) s_carry = 0;
  __syncthreads();
  for (int base = 0; base < n; base += 1024) {
    int i = base + tid;
    int v = (i < n) ? cnt[i] : 0;
    int x = v;
    #pragma unroll
    for (int off = 1; off < 64; off <<= 1) {
      int y = __shfl_up(x, off, 64);
      if (lane >= off) x += y;
    }
    if (lane == 63) wsum[w] = x;
    __syncthreads();
    if (w == 0 && lane < 16) {
      int t = wsum[lane];
      #pragma unroll
      for (int off = 1; off < 16; off <<= 1) {
        int y = __shfl_up(t, off, 64);
        if (lane >= off) t += y;
      }
      wsum[lane] = t; // inclusive over wave sums
    }
    __syncthreads();
    int waveoff = (w == 0) ? 0 : wsum[w - 1];
    int excl = s_carry + waveoff + x - v;
    if (i < n) { ptr[i] = excl; fill[i] = excl; }
    __syncthreads();
    if (tid == 0) s_carry += wsum[15];
    __syncthreads();
  }
  if (tid == 0) ptr[n] = s_carry;
}

__global__ void k_scatter(const int* __restrict__ rows, const int* __restrict__ cols,
                          const float* __restrict__ vals, int n,
                          int* __restrict__ fill, int* __restrict__ ccol,
                          float* __restrict__ cval) {
  int g = blockIdx.x * blockDim.x + threadIdx.x;
  if (g >= n) return;
  int p = atomicAdd(&fill[rows[g]], 1);
  ccol[p] = cols[g];
  cval[p] = vals[g];
}

// ---------------- dense GEMM v2: C(M x 96) += A(M x Kslice) @ B(K x 96) ----
// Structure: A streamed global->reg (reg double-buffer, 16-lane broadcast),
// B staged via async global_load_lds (no VGPR round-trip). 128 thr = 16tx x 8ty,
// BM=64 rows, per-thread 8x6. Per kk: 48 FMA vs 3 ds_read_b64 -> VALU-bound.
// 24KB LDS, ~130 VGPR -> 6 blocks (12 waves)/CU.
#define GBM 64
#define GBKC 64
typedef const __attribute__((address_space(1))) void* as1cv;
typedef __attribute__((address_space(3))) void* as3v;

__global__ __launch_bounds__(128, 3)
void k_gemm96v2(const float* __restrict__ A, const float* __restrict__ B,
                float* __restrict__ outIH, float* __restrict__ outIF,
                int M, int K, int kchunk) {
  __shared__ float Bs[GBKC * 96];   // 24 KB
  const int tid  = threadIdx.x;
  const int tx   = tid & 15;        // 16 col-groups of 6
  const int ty   = tid >> 4;        // 8 row-groups of 8
  const int wv   = tid >> 6;        // wave id 0..1
  const int lane = tid & 63;
  const int row0 = blockIdx.x * GBM;
  const int kbeg = blockIdx.y * kchunk;
  const int kend = min(K, kbeg + kchunk);   // kchunk is a multiple of GBKC

  // per-thread row pointers (clamped at M-tail; stores are guarded)
  const float* ap[8];
  #pragma unroll
  for (int i = 0; i < 8; ++i) {
    int gr = row0 + ty * 8 + i;
    if (gr > M - 1) gr = M - 1;
    ap[i] = A + (size_t)gr * K + kbeg;
  }

  float acc[8][6] = {};
  float4 a_cur[8], a_nxt[8];
  #pragma unroll
  for (int i = 0; i < 8; ++i) a_cur[i] = *(const float4*)(ap[i]);

  for (int c0 = kbeg; c0 < kend; c0 += GBKC) {
    // ---- async-stage B chunk (GBKC x 96 = 24KB): 12 x 1KB DMA per wave ----
    const float* gB = B + (size_t)c0 * 96;
    #pragma unroll
    for (int j = 0; j < 12; ++j) {
      int q0 = (wv * 12 + j) * 256;              // float index, wave-uniform
      __builtin_amdgcn_global_load_lds((as1cv)(gB + q0 + lane * 4),
                                       (as3v)(&Bs[q0]), 16, 0, 0);
    }
    __syncthreads();   // drains vmcnt (DMA complete) before reads

    const int koff = c0 - kbeg;
    const bool last_chunk = (c0 + GBKC >= kend);
    #pragma unroll
    for (int k4 = 0; k4 < GBKC / 4; ++k4) {
      // prefetch next k4-group (crosses into next chunk's first group too)
      if (!(last_chunk && k4 == GBKC / 4 - 1)) {
        int kn = koff + k4 * 4 + 4;
        #pragma unroll
        for (int i = 0; i < 8; ++i) a_nxt[i] = *(const float4*)(ap[i] + kn);
      }
      #pragma unroll
      for (int kk = 0; kk < 4; ++kk) {
        const float* br = &Bs[(size_t)(k4 * 4 + kk) * 96 + tx * 6];
        float2 b0 = *(const float2*)(br);
        float2 b1 = *(const float2*)(br + 2);
        float2 b2 = *(const float2*)(br + 4);
        float b[6] = {b0.x, b0.y, b1.x, b1.y, b2.x, b2.y};
        #pragma unroll
        for (int i = 0; i < 8; ++i) {
          float av = (kk == 0) ? a_cur[i].x : (kk == 1) ? a_cur[i].y
                   : (kk == 2) ? a_cur[i].z : a_cur[i].w;
          #pragma unroll
          for (int j = 0; j < 6; ++j) acc[i][j] += av * b[j];
        }
      }
      #pragma unroll
      for (int i = 0; i < 8; ++i) a_cur[i] = a_nxt[i];
    }
    __syncthreads();   // protect Bs from next chunk's DMA
  }

  // ---- epilogue: split-K partials via atomics (outputs pre-zeroed) ----
  #pragma unroll
  for (int i = 0; i < 8; ++i) {
    int gr = row0 + ty * 8 + i;
    if (gr >= M) continue;
    #pragma unroll
    for (int j = 0; j < 6; ++j) {
      int c = tx * 6 + j;
      float v = acc[i][j];
      if (c < 32) atomicAdd(&outIH[(size_t)gr * 32 + c], v);
      else        atomicAdd(&outIF[(size_t)gr * 64 + (c - 32)], v);
    }
  }
}

// ---------------- CSR SpMM ----------------
__global__ void k_spmm32(const int* __restrict__ ptr, const int* __restrict__ col,
                         const float* __restrict__ val, const float* __restrict__ x,
                         float* __restrict__ y, int nrows) {
  int g = blockIdx.x * blockDim.x + threadIdx.x;
  int row = g >> 5, lane = g & 31;
  if (row >= nrows) return;
  int jb = ptr[row], je = ptr[row + 1];
  float acc = 0.0f;
  for (int j = jb; j < je; ++j) acc += val[j] * x[(size_t)col[j] * 32 + lane];
  y[(size_t)row * 32 + lane] = acc;
}

__global__ void k_spmm64(const int* __restrict__ ptr, const int* __restrict__ col,
                         const float* __restrict__ val, const float* __restrict__ x,
                         float* __restrict__ y, int nrows,
                         const float* __restrict__ rowscale) {
  int g = blockIdx.x * blockDim.x + threadIdx.x;
  int row = g >> 6, lane = g & 63;
  if (row >= nrows) return;
  int jb = ptr[row], je = ptr[row + 1];
  float acc = 0.0f;
  for (int j = jb; j < je; ++j) acc += val[j] * x[(size_t)col[j] * 64 + lane];
  if (rowscale) acc *= rowscale[row];
  y[(size_t)row * 64 + lane] = acc;
}

// ---------------- gumbel softmax (in-place over n x 32) ----------------
__global__ void k_gumbel_softmax(float* __restrict__ logits, int nrows,
                                 uint32_t k0, uint32_t k1) {
  int row = blockIdx.x * 8 + (threadIdx.x >> 5);
  int c = threadIdx.x & 31;
  if (row >= nrows) return;
  int e = row * 32 + c;
  uint32_t b0, b1, bits;
#if JAX_PARTITIONABLE
  tf2x32(k0, k1, 0u, (uint32_t)e, b0, b1);
  bits = b0 ^ b1;
#else
  int half = nrows * 16;
  if (e < half) { tf2x32(k0, k1, (uint32_t)e, (uint32_t)(e + half), b0, b1); bits = b0; }
  else          { tf2x32(k0, k1, (uint32_t)(e - half), (uint32_t)e, b0, b1); bits = b1; }
#endif
  const float TINY = 1.1754943508222875e-38f;
  float f = __uint_as_float((bits >> 9) | 0x3F800000u) - 1.0f;  // [0,1)
  float u = fmaxf(TINY, f + TINY);
  float g = -logf(-logf(u));
  float x = (logits[e] + g) / 0.2f;
  float m = x;
  #pragma unroll
  for (int off = 16; off; off >>= 1) m = fmaxf(m, __shfl_xor(m, off, 32));
  float ex = expf(x - m);
  float s = ex;
  #pragma unroll
  for (int off = 16; off; off >>= 1) s += __shfl_xor(s, off, 32);
  logits[e] = ex / s;
}

// ---------------- small utility kernels ----------------
__global__ void k_copy(const float* __restrict__ s, float* __restrict__ d, int n) {
  int g = blockIdx.x * blockDim.x + threadIdx.x;
  if (g < n) d[g] = s[g];
}

__global__ void k_cge(const float* __restrict__ e0, const float* __restrict__ e1,
                      const float* __restrict__ e2, float* __restrict__ cge, int n) {
  int g = blockIdx.x * blockDim.x + threadIdx.x;
  if (g < n) cge[g] = (e0[g] + e1[g] + e2[g]) / 3.0f;
}

__global__ void k_l2norm_add(const float* __restrict__ x, float* __restrict__ msum,
                             int nrows) {
  int g = blockIdx.x * blockDim.x + threadIdx.x;
  int row = g >> 6, lane = g & 63;
  if (row >= nrows) return;
  size_t idx = (size_t)row * 64 + lane;
  float v = x[idx];
  float s = v * v;
  #pragma unroll
  for (int off = 32; off; off >>= 1) s += __shfl_xor(s, off, 64);
  float inv = 1.0f / fmaxf(sqrtf(s), 1e-12f);
  msum[idx] += v * inv;
}

// lat(32x64) += H(n x 32)^T @ X(n x 64)
__global__ void k_lat(const float* __restrict__ H, const float* __restrict__ X,
                      float* __restrict__ lat, int n) {
  int tid = threadIdx.x;
  int a = tid & 31, w = tid >> 5;        // w in 0..7 -> 8 cols each
  int i0 = blockIdx.x * 128;
  int iend = min(i0 + 128, n);
  float acc[8] = {};
  for (int i = i0; i < iend; ++i) {
    float h = H[(size_t)i * 32 + a];
    const float* xr = X + (size_t)i * 64 + w * 8;
    #pragma unroll
    for (int j = 0; j < 8; ++j) acc[j] += h * xr[j];
  }
  #pragma unroll
  for (int j = 0; j < 8; ++j) atomicAdd(&lat[a * 64 + w * 8 + j], acc[j]);
}

// out(n x 64) = H(n x 32) @ lat(32 x 64)
__global__ void k_hyper_out(const float* __restrict__ H, const float* __restrict__ lat,
                            float* __restrict__ out, int n) {
  __shared__ float ls[2048];
  int tid = threadIdx.x;
  for (int l = tid; l < 2048; l += 256) ls[l] = lat[l];
  __syncthreads();
  int row = blockIdx.x * 4 + (tid >> 6);
  int lane = tid & 63;
  if (row >= n) return;
  const float* h = H + (size_t)row * 32;
  float acc = 0.0f;
  #pragma unroll
  for (int a = 0; a < 32; ++a) acc += h[a] * ls[a * 64 + lane];
  out[(size_t)row * 64 + lane] = acc;
}

// B concat: bcat(K x 96) = [hyp(K x 32) | trs(K x 64)]
__global__ void k_concat_b(const float* __restrict__ hyp, const float* __restrict__ trs,
                           float* __restrict__ b, int K) {
  int g = blockIdx.x * blockDim.x + threadIdx.x;
  if (g >= K * 96) return;
  int k = g / 96, c = g % 96;
  b[g] = (c < 32) ? hyp[(size_t)k * 32 + c] : trs[(size_t)k * 64 + (c - 32)];
}

// final: lge = cge+msum; ghe from hyper outs; out = lge + 0.2*l2norm(ghe)
__global__ void k_final(const float* __restrict__ cge, const float* __restrict__ msum,
                        const float* __restrict__ o2, const float* __restrict__ o3,
                        const float* __restrict__ o4, const float* __restrict__ o5,
                        float* __restrict__ o0, float* __restrict__ o1) {
  int g = blockIdx.x * blockDim.x + threadIdx.x;
  int row = g >> 6, lane = g & 63;
  if (row >= NN) return;
  size_t idx = (size_t)row * 64 + lane;
  float lge = cge[idx] + msum[idx];
  float gv;
  size_t sub;
  if (row < NU) { sub = (size_t)row * 64 + lane;        gv = o2[sub] + o4[sub]; }
  else          { sub = (size_t)(row - NU) * 64 + lane; gv = o3[sub] + o5[sub]; }
  float s = gv * gv;
  #pragma unroll
  for (int off = 32; off; off >>= 1) s += __shfl_xor(s, off, 64);
  float inv = 1.0f / fmaxf(sqrtf(s), 1e-12f);
  float res = lge + 0.2f * gv * inv;
  if (row < NU) o0[sub] = res;
  else          o1[sub] = res;
}

static inline int cdiv(int a, int b) { return (a + b - 1) / b; }

extern "C" void kernel_launch(void* const* d_in, const int* in_sizes, int n_in,
                              void* d_out, int out_size, void* d_ws, size_t ws_size,
                              hipStream_t stream) {
  const float* Gu        = (const float*)d_in[0];
  const float* Gi        = (const float*)d_in[1];
  const float* feat_v    = (const float*)d_in[2];
  const float* feat_t    = (const float*)d_in[3];
  const float* trs_v     = (const float*)d_in[4];
  const float* trs_t     = (const float*)d_in[5];
  const float* hyp_v     = (const float*)d_in[6];
  const float* hyp_t     = (const float*)d_in[7];
  const float* inv_inters= (const float*)d_in[8];
  const float* adj_vals  = (const float*)d_in[9];
  const float* r_vals    = (const float*)d_in[10];
  const int*   adj_rows  = (const int*)d_in[11];
  const int*   adj_cols  = (const int*)d_in[12];
  const int*   r_rows    = (const int*)d_in[13];
  const int*   r_cols    = (const int*)d_in[14];

  float* W = (float*)d_ws;
  size_t off = 0;
  auto alloc = [&](size_t n) { float* p = W + off; off += (n + 63) & ~(size_t)63; return p; };
  int*   cntA  = (int*)alloc(NN);
  int*   ptrA  = (int*)alloc(NN + 1);
  int*   fillA = (int*)alloc(NN);
  int*   colA  = (int*)alloc(NNZ_A);
  float* valA  = alloc(NNZ_A);
  int*   cntR  = (int*)alloc(NU);
  int*   ptrR  = (int*)alloc(NU + 1);
  int*   fillR = (int*)alloc(NU);
  int*   colR  = (int*)alloc(NNZ_R);
  float* valR  = alloc(NNZ_R);
  float* bcv   = alloc((size_t)KV * 96);
  float* bct   = alloc((size_t)KT * 96);
  float* ihv   = alloc((size_t)NI * 32);
  float* iht   = alloc((size_t)NI * 32);
  float* itfv  = alloc((size_t)NI * 64);
  float* itft  = alloc((size_t)NI * 64);
  float* uhv   = alloc((size_t)NU * 32);
  float* uht   = alloc((size_t)NU * 32);
  float* ego   = alloc((size_t)NN * 64);   // later reused as mge0
  float* t1b   = alloc((size_t)NN * 64);   // later reused as mge1
  float* t2b   = alloc((size_t)NN * 64);
  float* cgeb  = alloc((size_t)NN * 64);
  float* msum  = alloc((size_t)NN * 64);
  float* latv  = alloc(2048);
  float* latt  = alloc(2048);
  (void)ws_size; (void)in_sizes; (void)n_in; (void)out_size;

  float* o0 = (float*)d_out;
  float* o1 = o0 + (size_t)NU * 64;
  float* o2 = o1 + (size_t)NI * 64;
  float* o3 = o2 + (size_t)NU * 64;
  float* o4 = o3 + (size_t)NI * 64;
  float* o5 = o4 + (size_t)NU * 64;

  // ---- PRNG key derivation on host: key(42) -> fold_in(m) -> split ----
  uint32_t ks[2][4];
  for (int m = 0; m < 2; ++m) {
    uint32_t a, b;
    tf2x32(0u, 42u, 0u, (uint32_t)m, a, b);
#if JAX_PARTITIONABLE
    uint32_t p0, p1, q0, q1;
    tf2x32(a, b, 0u, 0u, p0, p1);   // k1
    tf2x32(a, b, 0u, 1u, q0, q1);   // k2
    ks[m][0] = p0; ks[m][1] = p1; ks[m][2] = q0; ks[m][3] = q1;
#else
    uint32_t p0, p1, q0, q1;
    tf2x32(a, b, 0u, 2u, p0, p1);
    tf2x32(a, b, 1u, 3u, q0, q1);
    ks[m][0] = p0; ks[m][1] = q0; ks[m][2] = p1; ks[m][3] = q1;
#endif
  }

  // ---- zero init ----
  hipMemsetAsync(cntA, 0, (size_t)NN * 4, stream);
  hipMemsetAsync(cntR, 0, (size_t)NU * 4, stream);
  hipMemsetAsync(latv, 0, 2048 * 4, stream);
  hipMemsetAsync(latt, 0, 2048 * 4, stream);
  hipMemsetAsync(msum, 0, (size_t)NN * 64 * 4, stream);
  // split-K GEMM outputs must start at zero (atomicAdd accumulation)
  hipMemsetAsync(ihv,  0, (size_t)NI * 32 * 4, stream);
  hipMemsetAsync(iht,  0, (size_t)NI * 32 * 4, stream);
  hipMemsetAsync(itfv, 0, (size_t)NI * 64 * 4, stream);
  hipMemsetAsync(itft, 0, (size_t)NI * 64 * 4, stream);

  // ---- CSR build for adj and R ----
  k_hist<<<cdiv(NNZ_A, 256), 256, 0, stream>>>(adj_rows, NNZ_A, cntA);
  k_hist<<<cdiv(NNZ_R, 256), 256, 0, stream>>>(r_rows, NNZ_R, cntR);
  k_exscan<<<1, 1024, 0, stream>>>(cntA, ptrA, fillA, NN);
  k_exscan<<<1, 1024, 0, stream>>>(cntR, ptrR, fillR, NU);
  k_scatter<<<cdiv(NNZ_A, 256), 256, 0, stream>>>(adj_rows, adj_cols, adj_vals, NNZ_A, fillA, colA, valA);
  k_scatter<<<cdiv(NNZ_R, 256), 256, 0, stream>>>(r_rows, r_cols, r_vals, NNZ_R, fillR, colR, valR);

  // ---- dense GEMMs: [ih_logits | item_feats] = feat @ [hyp | trs] ----
  k_concat_b<<<cdiv(KV * 96, 256), 256, 0, stream>>>(hyp_v, trs_v, bcv, KV);
  k_concat_b<<<cdiv(KT * 96, 256), 256, 0, stream>>>(hyp_t, trs_t, bct, KT);
  // v: split-K x4 (kchunk=1024 = 16 chunks of 64); t: split-K x2 (kchunk=192)
  {
    dim3 gv(cdiv(NI, GBM), 4);
    k_gemm96v2<<<gv, 128, 0, stream>>>(feat_v, bcv, ihv, itfv, NI, KV, 1024);
    dim3 gt(cdiv(NI, GBM), 2);
    k_gemm96v2<<<gt, 128, 0, stream>>>(feat_t, bct, iht, itft, NI, KT, 192);
  }

  // ---- uh_logits = R @ ih_logits (before softmax!) ----
  k_spmm32<<<cdiv(NU * 32, 256), 256, 0, stream>>>(ptrR, colR, valR, ihv, uhv, NU);
  k_spmm32<<<cdiv(NU * 32, 256), 256, 0, stream>>>(ptrR, colR, valR, iht, uht, NU);

  // ---- gumbel softmax in place ----
  k_gumbel_softmax<<<cdiv(NI, 8), 256, 0, stream>>>(ihv, NI, ks[0][0], ks[0][1]);
  k_gumbel_softmax<<<cdiv(NU, 8), 256, 0, stream>>>(uhv, NU, ks[0][2], ks[0][3]);
  k_gumbel_softmax<<<cdiv(NI, 8), 256, 0, stream>>>(iht, NI, ks[1][0], ks[1][1]);
  k_gumbel_softmax<<<cdiv(NU, 8), 256, 0, stream>>>(uht, NU, ks[1][2], ks[1][3]);

  // ---- UI propagation: cge = (e0 + e1 + e2)/3 ----
  k_copy<<<cdiv(NU * 64, 256), 256, 0, stream>>>(Gu, ego, NU * 64);
  k_copy<<<cdiv(NI * 64, 256), 256, 0, stream>>>(Gi, ego + (size_t)NU * 64, NI * 64);
  k_spmm64<<<cdiv(NN * 64, 256), 256, 0, stream>>>(ptrA, colA, valA, ego, t1b, NN, nullptr);
  k_spmm64<<<cdiv(NN * 64, 256), 256, 0, stream>>>(ptrA, colA, valA, t1b, t2b, NN, nullptr);
  k_cge<<<cdiv(NN * 64, 256), 256, 0, stream>>>(ego, t1b, t2b, cgeb, NN * 64);

  // ---- modality graph embeddings (reuse ego as mge0, t1b as mge1) ----
  // v
  k_spmm64<<<cdiv(NU * 64, 256), 256, 0, stream>>>(ptrR, colR, valR, itfv, ego, NU, inv_inters);
  k_copy<<<cdiv(NI * 64, 256), 256, 0, stream>>>(itfv, ego + (size_t)NU * 64, NI * 64);
  k_spmm64<<<cdiv(NN * 64, 256), 256, 0, stream>>>(ptrA, colA, valA, ego, t1b, NN, nullptr);
  k_l2norm_add<<<cdiv(NN * 64, 256), 256, 0, stream>>>(t1b, msum, NN);
  // t
  k_spmm64<<<cdiv(NU * 64, 256), 256, 0, stream>>>(ptrR, colR, valR, itft, ego, NU, inv_inters);
  k_copy<<<cdiv(NI * 64, 256), 256, 0, stream>>>(itft, ego + (size_t)NU * 64, NI * 64);
  k_spmm64<<<cdiv(NN * 64, 256), 256, 0, stream>>>(ptrA, colA, valA, ego, t1b, NN, nullptr);
  k_l2norm_add<<<cdiv(NN * 64, 256), 256, 0, stream>>>(t1b, msum, NN);

  // ---- hypergraph pass: lat = ih^T @ item_cge; u_ret = uh@lat; i_ret = ih@lat ----
  const float* item_cge = cgeb + (size_t)NU * 64;
  k_lat<<<cdiv(NI, 128), 256, 0, stream>>>(ihv, item_cge, latv, NI);
  k_hyper_out<<<cdiv(NU, 4), 256, 0, stream>>>(uhv, latv, o2, NU);
  k_hyper_out<<<cdiv(NI, 4), 256, 0, stream>>>(ihv, latv, o3, NI);
  k_lat<<<cdiv(NI, 128), 256, 0, stream>>>(iht, item_cge, latt, NI);
  k_hyper_out<<<cdiv(NU, 4), 256, 0, stream>>>(uht, latt, o4, NU);
  k_hyper_out<<<cdiv(NI, 4), 256, 0, stream>>>(iht, latt, o5, NI);

  // ---- final combine ----
  k_final<<<cdiv(NN * 64, 256), 256, 0, stream>>>(cgeb, msum, o2, o3, o4, o5, o0, o1);
}

// Round 3
// 2909.727 us; speedup vs baseline: 3.3831x; 3.3831x over previous
//
#include <hip/hip_runtime.h>
#include <stdint.h>

// ---------------- problem constants ----------------
#define NU 50000
#define NI 30000
#define NN 80000   // NU+NI
#define EK 64
#define HK 32
#define KV 4096
#define KT 384
#define NNZ_A 2000000
#define NNZ_R 1000000

#define JAX_PARTITIONABLE 1

// ---------------- threefry2x32 (20 rounds) ----------------
__host__ __device__ static inline void tf2x32(uint32_t k0, uint32_t k1,
                                              uint32_t x0, uint32_t x1,
                                              uint32_t& o0, uint32_t& o1) {
  uint32_t ks2 = k0 ^ k1 ^ 0x1BD11BDAu;
#define ROTL(x,d) (((x)<<(d))|((x)>>(32-(d))))
#define RND(r) { x0 += x1; x1 = ROTL(x1,r); x1 ^= x0; }
  x0 += k0; x1 += k1;
  RND(13) RND(15) RND(26) RND(6)
  x0 += k1;  x1 += ks2 + 1u;
  RND(17) RND(29) RND(16) RND(24)
  x0 += ks2; x1 += k0 + 2u;
  RND(13) RND(15) RND(26) RND(6)
  x0 += k0;  x1 += k1 + 3u;
  RND(17) RND(29) RND(16) RND(24)
  x0 += k1;  x1 += ks2 + 4u;
  RND(13) RND(15) RND(26) RND(6)
  x0 += ks2; x1 += k0 + 5u;
  o0 = x0; o1 = x1;
#undef RND
#undef ROTL
}

// ---------------- CSR build ----------------
__global__ void k_hist(const int* __restrict__ rows, int n, int* __restrict__ cnt) {
  int g = blockIdx.x * blockDim.x + threadIdx.x;
  if (g < n) atomicAdd(&cnt[rows[g]], 1);
}

__global__ void k_exscan(const int* __restrict__ cnt, int* __restrict__ ptr,
                         int* __restrict__ fill, int n) {
  __shared__ int wsum[16];
  __shared__ int s_carry;
  int tid = threadIdx.x;
  int lane = tid & 63, w = tid >> 6;
  if (tid == 0) s_carry = 0;
  __syncthreads();
  for (int base = 0; base < n; base += 1024) {
    int i = base + tid;
    int v = (i < n) ? cnt[i] : 0;
    int x = v;
    #pragma unroll
    for (int off = 1; off < 64; off <<= 1) {
      int y = __shfl_up(x, off, 64);
      if (lane >= off) x += y;
    }
    if (lane == 63) wsum[w] = x;
    __syncthreads();
    if (w == 0 && lane < 16) {
      int t = wsum[lane];
      #pragma unroll
      for (int off = 1; off < 16; off <<= 1) {
        int y = __shfl_up(t, off, 64);
        if (lane >= off) t += y;
      }
      wsum[lane] = t; // inclusive over wave sums
    }
    __syncthreads();
    int waveoff = (w == 0) ? 0 : wsum[w - 1];
    int excl = s_carry + waveoff + x - v;
    if (i < n) { ptr[i] = excl; fill[i] = excl; }
    __syncthreads();
    if (tid == 0) s_carry += wsum[15];
    __syncthreads();
  }
  if (tid == 0) ptr[n] = s_carry;
}

__global__ void k_scatter(const int* __restrict__ rows, const int* __restrict__ cols,
                          const float* __restrict__ vals, int n,
                          int* __restrict__ fill, int* __restrict__ ccol,
                          float* __restrict__ cval) {
  int g = blockIdx.x * blockDim.x + threadIdx.x;
  if (g >= n) return;
  int p = atomicAdd(&fill[rows[g]], 1);
  ccol[p] = cols[g];
  cval[p] = vals[g];
}

// ---------------- dense GEMM v3: P[split] = A(32-row tile x Kslice) @ B ----
// A: global->reg streamed, one float4 per row per k4, reg double-buffer (a_nxt).
// B: LDS double-buffered via async global_load_lds; 1 barrier per 16-k chunk.
// 128 thr = 16tx x 8ty, 4 rows/thread, acc 4x6. ~90 VGPR, 12 KB LDS.
// NOTE: empirically hipcc treats launch_bounds 2nd arg as min BLOCKS/EU:
// VGPR cap = 512/(arg * waves_per_block). (128,2) -> cap 128. (r2: (128,3)->84+spill)
#define GBM 32
#define GBKC 16
typedef const __attribute__((address_space(1))) void* as1cv;
typedef __attribute__((address_space(3))) void* as3v;

__global__ __launch_bounds__(128, 2)
void k_gemm96v3(const float* __restrict__ A, const float* __restrict__ B,
                float* __restrict__ P,    // partials: P + by*M*96
                int M, int K, int kchunk) {
  __shared__ __align__(16) float Bs[2][GBKC * 96];   // 2 x 6 KB
  const int tid  = threadIdx.x;
  const int tx   = tid & 15;        // 16 col-groups of 6
  const int ty   = tid >> 4;        // 8 row-groups of 4
  const int wv   = tid >> 6;        // wave 0..1
  const int lane = tid & 63;
  const int row0 = blockIdx.x * GBM;
  const int kbeg = blockIdx.y * kchunk;
  const int nchunk = kchunk / GBKC;     // kchunk multiple of GBKC, exact K fit

  const float* ap[4];
  #pragma unroll
  for (int i = 0; i < 4; ++i) {
    int gr = row0 + ty * 4 + i;
    if (gr > M - 1) gr = M - 1;       // clamp loads; stores guarded
    ap[i] = A + (size_t)gr * K + kbeg;
  }

  // prologue: stage chunk 0 B + first A quad
  {
    const float* gB = B + (size_t)kbeg * 96;
    #pragma unroll
    for (int j = 0; j < 3; ++j) {
      int q0 = (wv * 3 + j) * 256;    // wave-uniform float index (1KB per DMA)
      __builtin_amdgcn_global_load_lds((as1cv)(gB + q0 + lane * 4),
                                       (as3v)(&Bs[0][q0]), 16, 0, 0);
    }
  }
  float4 a_cur[4], a_nxt[4];
  #pragma unroll
  for (int i = 0; i < 4; ++i) a_cur[i] = *(const float4*)(ap[i]);
  __syncthreads();                    // vmcnt(0): chunk0 + a_cur ready

  float acc[4][6] = {};
  for (int t = 0; t < nchunk; ++t) {
    if (t + 1 < nchunk) {             // issue next-chunk DMA early (overlaps compute)
      const float* gB = B + (size_t)(kbeg + (t + 1) * GBKC) * 96;
      float* bdst = Bs[(t + 1) & 1];
      #pragma unroll
      for (int j = 0; j < 3; ++j) {
        int q0 = (wv * 3 + j) * 256;
        __builtin_amdgcn_global_load_lds((as1cv)(gB + q0 + lane * 4),
                                         (as3v)(&bdst[q0]), 16, 0, 0);
      }
    }
    const float* bs = Bs[t & 1];
    const int koff = t * GBKC;
    #pragma unroll
    for (int k4 = 0; k4 < GBKC / 4; ++k4) {
      const bool last = (t == nchunk - 1) && (k4 == GBKC / 4 - 1);
      if (!last) {
        int kn = koff + k4 * 4 + 4;
        #pragma unroll
        for (int i = 0; i < 4; ++i) a_nxt[i] = *(const float4*)(ap[i] + kn);
      }
      #pragma unroll
      for (int kk = 0; kk < 4; ++kk) {
        const float* br = &bs[(k4 * 4 + kk) * 96 + tx * 6];
        float2 b0 = *(const float2*)(br);       // banks: 16 distinct even pairs,
        float2 b1 = *(const float2*)(br + 2);   // 4-way ty-broadcast -> conflict-free
        float2 b2 = *(const float2*)(br + 4);
        float b[6] = {b0.x, b0.y, b1.x, b1.y, b2.x, b2.y};
        #pragma unroll
        for (int i = 0; i < 4; ++i) {
          float av = (kk == 0) ? a_cur[i].x : (kk == 1) ? a_cur[i].y
                   : (kk == 2) ? a_cur[i].z : a_cur[i].w;
          #pragma unroll
          for (int j = 0; j < 6; ++j) acc[i][j] += av * b[j];
        }
      }
      if (!last) {
        #pragma unroll
        for (int i = 0; i < 4; ++i) a_cur[i] = a_nxt[i];
      }
    }
    __syncthreads();   // drains vmcnt: next chunk landed; buf[t] free for overwrite
  }

  // epilogue: per-split partial (no atomics; reduced later)
  float* pb = P + (size_t)blockIdx.y * M * 96;
  #pragma unroll
  for (int i = 0; i < 4; ++i) {
    int gr = row0 + ty * 4 + i;
    if (gr >= M) continue;
    float* pr = pb + (size_t)gr * 96 + tx * 6;
    #pragma unroll
    for (int j = 0; j < 6; ++j) pr[j] = acc[i][j];
  }
}

// reduce split-K partials: out cols 0..31 -> IH, 32..95 -> IF
__global__ void k_reduce_splits(const float* __restrict__ P, int nsplit, int M,
                                float* __restrict__ outIH, float* __restrict__ outIF) {
  int g = blockIdx.x * blockDim.x + threadIdx.x;
  if (g >= M * 96) return;
  float s = 0.0f;
  for (int sp = 0; sp < nsplit; ++sp) s += P[(size_t)sp * M * 96 + g];
  int r = g / 96, c = g - (g / 96) * 96;
  if (c < 32) outIH[(size_t)r * 32 + c] = s;
  else        outIF[(size_t)r * 64 + (c - 32)] = s;
}

// ---------------- CSR SpMM ----------------
__global__ void k_spmm32(const int* __restrict__ ptr, const int* __restrict__ col,
                         const float* __restrict__ val, const float* __restrict__ x,
                         float* __restrict__ y, int nrows) {
  int g = blockIdx.x * blockDim.x + threadIdx.x;
  int row = g >> 5, lane = g & 31;
  if (row >= nrows) return;
  int jb = ptr[row], je = ptr[row + 1];
  float acc = 0.0f;
  for (int j = jb; j < je; ++j) acc += val[j] * x[(size_t)col[j] * 32 + lane];
  y[(size_t)row * 32 + lane] = acc;
}

__global__ void k_spmm64(const int* __restrict__ ptr, const int* __restrict__ col,
                         const float* __restrict__ val, const float* __restrict__ x,
                         float* __restrict__ y, int nrows,
                         const float* __restrict__ rowscale) {
  int g = blockIdx.x * blockDim.x + threadIdx.x;
  int row = g >> 6, lane = g & 63;
  if (row >= nrows) return;
  int jb = ptr[row], je = ptr[row + 1];
  float acc = 0.0f;
  for (int j = jb; j < je; ++j) acc += val[j] * x[(size_t)col[j] * 64 + lane];
  if (rowscale) acc *= rowscale[row];
  y[(size_t)row * 64 + lane] = acc;
}

// ---------------- gumbel softmax (in-place over n x 32) ----------------
__global__ void k_gumbel_softmax(float* __restrict__ logits, int nrows,
                                 uint32_t k0, uint32_t k1) {
  int row = blockIdx.x * 8 + (threadIdx.x >> 5);
  int c = threadIdx.x & 31;
  if (row >= nrows) return;
  int e = row * 32 + c;
  uint32_t b0, b1, bits;
#if JAX_PARTITIONABLE
  tf2x32(k0, k1, 0u, (uint32_t)e, b0, b1);
  bits = b0 ^ b1;
#else
  int half = nrows * 16;
  if (e < half) { tf2x32(k0, k1, (uint32_t)e, (uint32_t)(e + half), b0, b1); bits = b0; }
  else          { tf2x32(k0, k1, (uint32_t)(e - half), (uint32_t)e, b0, b1); bits = b1; }
#endif
  const float TINY = 1.1754943508222875e-38f;
  float f = __uint_as_float((bits >> 9) | 0x3F800000u) - 1.0f;  // [0,1)
  float u = fmaxf(TINY, f + TINY);
  float g = -logf(-logf(u));
  float x = (logits[e] + g) / 0.2f;
  float m = x;
  #pragma unroll
  for (int off = 16; off; off >>= 1) m = fmaxf(m, __shfl_xor(m, off, 32));
  float ex = expf(x - m);
  float s = ex;
  #pragma unroll
  for (int off = 16; off; off >>= 1) s += __shfl_xor(s, off, 32);
  logits[e] = ex / s;
}

// ---------------- small utility kernels ----------------
__global__ void k_copy(const float* __restrict__ s, float* __restrict__ d, int n) {
  int g = blockIdx.x * blockDim.x + threadIdx.x;
  if (g < n) d[g] = s[g];
}

__global__ void k_cge(const float* __restrict__ e0, const float* __restrict__ e1,
                      const float* __restrict__ e2, float* __restrict__ cge, int n) {
  int g = blockIdx.x * blockDim.x + threadIdx.x;
  if (g < n) cge[g] = (e0[g] + e1[g] + e2[g]) / 3.0f;
}

__global__ void k_l2norm_add(const float* __restrict__ x, float* __restrict__ msum,
                             int nrows) {
  int g = blockIdx.x * blockDim.x + threadIdx.x;
  int row = g >> 6, lane = g & 63;
  if (row >= nrows) return;
  size_t idx = (size_t)row * 64 + lane;
  float v = x[idx];
  float s = v * v;
  #pragma unroll
  for (int off = 32; off; off >>= 1) s += __shfl_xor(s, off, 64);
  float inv = 1.0f / fmaxf(sqrtf(s), 1e-12f);
  msum[idx] += v * inv;
}

// lat(32x64) += H(n x 32)^T @ X(n x 64)
__global__ void k_lat(const float* __restrict__ H, const float* __restrict__ X,
                      float* __restrict__ lat, int n) {
  int tid = threadIdx.x;
  int a = tid & 31, w = tid >> 5;        // w in 0..7 -> 8 cols each
  int i0 = blockIdx.x * 128;
  int iend = min(i0 + 128, n);
  float acc[8] = {};
  for (int i = i0; i < iend; ++i) {
    float h = H[(size_t)i * 32 + a];
    const float* xr = X + (size_t)i * 64 + w * 8;
    #pragma unroll
    for (int j = 0; j < 8; ++j) acc[j] += h * xr[j];
  }
  #pragma unroll
  for (int j = 0; j < 8; ++j) atomicAdd(&lat[a * 64 + w * 8 + j], acc[j]);
}

// out(n x 64) = H(n x 32) @ lat(32 x 64)
__global__ void k_hyper_out(const float* __restrict__ H, const float* __restrict__ lat,
                            float* __restrict__ out, int n) {
  __shared__ float ls[2048];
  int tid = threadIdx.x;
  for (int l = tid; l < 2048; l += 256) ls[l] = lat[l];
  __syncthreads();
  int row = blockIdx.x * 4 + (tid >> 6);
  int lane = tid & 63;
  if (row >= n) return;
  const float* h = H + (size_t)row * 32;
  float acc = 0.0f;
  #pragma unroll
  for (int a = 0; a < 32; ++a) acc += h[a] * ls[a * 64 + lane];
  out[(size_t)row * 64 + lane] = acc;
}

// B concat: bcat(K x 96) = [hyp(K x 32) | trs(K x 64)]
__global__ void k_concat_b(const float* __restrict__ hyp, const float* __restrict__ trs,
                           float* __restrict__ b, int K) {
  int g = blockIdx.x * blockDim.x + threadIdx.x;
  if (g >= K * 96) return;
  int k = g / 96, c = g % 96;
  b[g] = (c < 32) ? hyp[(size_t)k * 32 + c] : trs[(size_t)k * 64 + (c - 32)];
}

// final: lge = cge+msum; ghe from hyper outs; out = lge + 0.2*l2norm(ghe)
__global__ void k_final(const float* __restrict__ cge, const float* __restrict__ msum,
                        const float* __restrict__ o2, const float* __restrict__ o3,
                        const float* __restrict__ o4, const float* __restrict__ o5,
                        float* __restrict__ o0, float* __restrict__ o1) {
  int g = blockIdx.x * blockDim.x + threadIdx.x;
  int row = g >> 6, lane = g & 63;
  if (row >= NN) return;
  size_t idx = (size_t)row * 64 + lane;
  float lge = cge[idx] + msum[idx];
  float gv;
  size_t sub;
  if (row < NU) { sub = (size_t)row * 64 + lane;        gv = o2[sub] + o4[sub]; }
  else          { sub = (size_t)(row - NU) * 64 + lane; gv = o3[sub] + o5[sub]; }
  float s = gv * gv;
  #pragma unroll
  for (int off = 32; off; off >>= 1) s += __shfl_xor(s, off, 64);
  float inv = 1.0f / fmaxf(sqrtf(s), 1e-12f);
  float res = lge + 0.2f * gv * inv;
  if (row < NU) o0[sub] = res;
  else          o1[sub] = res;
}

static inline int cdiv(int a, int b) { return (a + b - 1) / b; }

extern "C" void kernel_launch(void* const* d_in, const int* in_sizes, int n_in,
                              void* d_out, int out_size, void* d_ws, size_t ws_size,
                              hipStream_t stream) {
  const float* Gu        = (const float*)d_in[0];
  const float* Gi        = (const float*)d_in[1];
  const float* feat_v    = (const float*)d_in[2];
  const float* feat_t    = (const float*)d_in[3];
  const float* trs_v     = (const float*)d_in[4];
  const float* trs_t     = (const float*)d_in[5];
  const float* hyp_v     = (const float*)d_in[6];
  const float* hyp_t     = (const float*)d_in[7];
  const float* inv_inters= (const float*)d_in[8];
  const float* adj_vals  = (const float*)d_in[9];
  const float* r_vals    = (const float*)d_in[10];
  const int*   adj_rows  = (const int*)d_in[11];
  const int*   adj_cols  = (const int*)d_in[12];
  const int*   r_rows    = (const int*)d_in[13];
  const int*   r_cols    = (const int*)d_in[14];

  float* W = (float*)d_ws;
  size_t off = 0;
  auto alloc = [&](size_t n) { float* p = W + off; off += (n + 63) & ~(size_t)63; return p; };
  int*   cntA  = (int*)alloc(NN);
  int*   ptrA  = (int*)alloc(NN + 1);
  int*   fillA = (int*)alloc(NN);
  int*   colA  = (int*)alloc(NNZ_A);
  float* valA  = alloc(NNZ_A);
  int*   cntR  = (int*)alloc(NU);
  int*   ptrR  = (int*)alloc(NU + 1);
  int*   fillR = (int*)alloc(NU);
  int*   colR  = (int*)alloc(NNZ_R);
  float* valR  = alloc(NNZ_R);
  float* bcv   = alloc((size_t)KV * 96);
  float* bct   = alloc((size_t)KT * 96);
  float* ihv   = alloc((size_t)NI * 32);
  float* iht   = alloc((size_t)NI * 32);
  float* itfv  = alloc((size_t)NI * 64);
  float* itft  = alloc((size_t)NI * 64);
  float* uhv   = alloc((size_t)NU * 32);
  float* uht   = alloc((size_t)NU * 32);
  float* ego   = alloc((size_t)NN * 64);   // later reused as mge0
  float* t1b   = alloc((size_t)NN * 64);   // later reused as mge1
  float* t2b   = alloc((size_t)NN * 64);
  float* cgeb  = alloc((size_t)NN * 64);
  float* msum  = alloc((size_t)NN * 64);
  float* latv  = alloc(2048);
  float* latt  = alloc(2048);
  (void)ws_size; (void)in_sizes; (void)n_in; (void)out_size;

  // Split-K partial buffers ALIAS later-stage temporaries (all 64-float-aligned
  // sizes -> ego..msum are contiguous). pv: 4*NI*96 = 11.52M floats fits in
  // ego+t1b+t2b (15.36M). pt: 2*NI*96 = 5.76M fits in cgeb+msum (10.24M).
  // Safe because: reduces run BEFORE ego/cgeb/msum are first written, and the
  // msum memset is moved to after the reduces (stream-ordered).
  float* pv = ego;
  float* pt = cgeb;

  float* o0 = (float*)d_out;
  float* o1 = o0 + (size_t)NU * 64;
  float* o2 = o1 + (size_t)NI * 64;
  float* o3 = o2 + (size_t)NU * 64;
  float* o4 = o3 + (size_t)NI * 64;
  float* o5 = o4 + (size_t)NU * 64;

  // ---- PRNG key derivation on host: key(42) -> fold_in(m) -> split ----
  uint32_t ks[2][4];
  for (int m = 0; m < 2; ++m) {
    uint32_t a, b;
    tf2x32(0u, 42u, 0u, (uint32_t)m, a, b);
#if JAX_PARTITIONABLE
    uint32_t p0, p1, q0, q1;
    tf2x32(a, b, 0u, 0u, p0, p1);   // k1
    tf2x32(a, b, 0u, 1u, q0, q1);   // k2
    ks[m][0] = p0; ks[m][1] = p1; ks[m][2] = q0; ks[m][3] = q1;
#else
    uint32_t p0, p1, q0, q1;
    tf2x32(a, b, 0u, 2u, p0, p1);
    tf2x32(a, b, 1u, 3u, q0, q1);
    ks[m][0] = p0; ks[m][1] = q0; ks[m][2] = p1; ks[m][3] = q1;
#endif
  }

  // ---- zero init ----
  hipMemsetAsync(cntA, 0, (size_t)NN * 4, stream);
  hipMemsetAsync(cntR, 0, (size_t)NU * 4, stream);
  hipMemsetAsync(latv, 0, 2048 * 4, stream);
  hipMemsetAsync(latt, 0, 2048 * 4, stream);

  // ---- CSR build for adj and R ----
  k_hist<<<cdiv(NNZ_A, 256), 256, 0, stream>>>(adj_rows, NNZ_A, cntA);
  k_hist<<<cdiv(NNZ_R, 256), 256, 0, stream>>>(r_rows, NNZ_R, cntR);
  k_exscan<<<1, 1024, 0, stream>>>(cntA, ptrA, fillA, NN);
  k_exscan<<<1, 1024, 0, stream>>>(cntR, ptrR, fillR, NU);
  k_scatter<<<cdiv(NNZ_A, 256), 256, 0, stream>>>(adj_rows, adj_cols, adj_vals, NNZ_A, fillA, colA, valA);
  k_scatter<<<cdiv(NNZ_R, 256), 256, 0, stream>>>(r_rows, r_cols, r_vals, NNZ_R, fillR, colR, valR);

  // ---- dense GEMMs: [ih_logits | item_feats] = feat @ [hyp | trs] ----
  k_concat_b<<<cdiv(KV * 96, 256), 256, 0, stream>>>(hyp_v, trs_v, bcv, KV);
  k_concat_b<<<cdiv(KT * 96, 256), 256, 0, stream>>>(hyp_t, trs_t, bct, KT);
  {
    dim3 gv(cdiv(NI, GBM), 4);   // kchunk 1024 = 64 chunks of 16
    k_gemm96v3<<<gv, 128, 0, stream>>>(feat_v, bcv, pv, NI, KV, 1024);
    dim3 gt(cdiv(NI, GBM), 2);   // kchunk 192 = 12 chunks of 16
    k_gemm96v3<<<gt, 128, 0, stream>>>(feat_t, bct, pt, NI, KT, 192);
    k_reduce_splits<<<cdiv(NI * 96, 256), 256, 0, stream>>>(pv, 4, NI, ihv, itfv);
    k_reduce_splits<<<cdiv(NI * 96, 256), 256, 0, stream>>>(pt, 2, NI, iht, itft);
  }
  // msum zero AFTER reduces (pt tail aliases msum head)
  hipMemsetAsync(msum, 0, (size_t)NN * 64 * 4, stream);

  // ---- uh_logits = R @ ih_logits (before softmax!) ----
  k_spmm32<<<cdiv(NU * 32, 256), 256, 0, stream>>>(ptrR, colR, valR, ihv, uhv, NU);
  k_spmm32<<<cdiv(NU * 32, 256), 256, 0, stream>>>(ptrR, colR, valR, iht, uht, NU);

  // ---- gumbel softmax in place ----
  k_gumbel_softmax<<<cdiv(NI, 8), 256, 0, stream>>>(ihv, NI, ks[0][0], ks[0][1]);
  k_gumbel_softmax<<<cdiv(NU, 8), 256, 0, stream>>>(uhv, NU, ks[0][2], ks[0][3]);
  k_gumbel_softmax<<<cdiv(NI, 8), 256, 0, stream>>>(iht, NI, ks[1][0], ks[1][1]);
  k_gumbel_softmax<<<cdiv(NU, 8), 256, 0, stream>>>(uht, NU, ks[1][2], ks[1][3]);

  // ---- UI propagation: cge = (e0 + e1 + e2)/3 ----
  k_copy<<<cdiv(NU * 64, 256), 256, 0, stream>>>(Gu, ego, NU * 64);
  k_copy<<<cdiv(NI * 64, 256), 256, 0, stream>>>(Gi, ego + (size_t)NU * 64, NI * 64);
  k_spmm64<<<cdiv(NN * 64, 256), 256, 0, stream>>>(ptrA, colA, valA, ego, t1b, NN, nullptr);
  k_spmm64<<<cdiv(NN * 64, 256), 256, 0, stream>>>(ptrA, colA, valA, t1b, t2b, NN, nullptr);
  k_cge<<<cdiv(NN * 64, 256), 256, 0, stream>>>(ego, t1b, t2b, cgeb, NN * 64);

  // ---- modality graph embeddings (reuse ego as mge0, t1b as mge1) ----
  // v
  k_spmm64<<<cdiv(NU * 64, 256), 256, 0, stream>>>(ptrR, colR, valR, itfv, ego, NU, inv_inters);
  k_copy<<<cdiv(NI * 64, 256), 256, 0, stream>>>(itfv, ego + (size_t)NU * 64, NI * 64);
  k_spmm64<<<cdiv(NN * 64, 256), 256, 0, stream>>>(ptrA, colA, valA, ego, t1b, NN, nullptr);
  k_l2norm_add<<<cdiv(NN * 64, 256), 256, 0, stream>>>(t1b, msum, NN);
  // t
  k_spmm64<<<cdiv(NU * 64, 256), 256, 0, stream>>>(ptrR, colR, valR, itft, ego, NU, inv_inters);
  k_copy<<<cdiv(NI * 64, 256), 256, 0, stream>>>(itft, ego + (size_t)NU * 64, NI * 64);
  k_spmm64<<<cdiv(NN * 64, 256), 256, 0, stream>>>(ptrA, colA, valA, ego, t1b, NN, nullptr);
  k_l2norm_add<<<cdiv(NN * 64, 256), 256, 0, stream>>>(t1b, msum, NN);

  // ---- hypergraph pass: lat = ih^T @ item_cge; u_ret = uh@lat; i_ret = ih@lat ----
  const float* item_cge = cgeb + (size_t)NU * 64;
  k_lat<<<cdiv(NI, 128), 256, 0, stream>>>(ihv, item_cge, latv, NI);
  k_hyper_out<<<cdiv(NU, 4), 256, 0, stream>>>(uhv, latv, o2, NU);
  k_hyper_out<<<cdiv(NI, 4), 256, 0, stream>>>(ihv, latv, o3, NI);
  k_lat<<<cdiv(NI, 128), 256, 0, stream>>>(iht, item_cge, latt, NI);
  k_hyper_out<<<cdiv(NU, 4), 256, 0, stream>>>(uht, latt, o4, NU);
  k_hyper_out<<<cdiv(NI, 4), 256, 0, stream>>>(iht, latt, o5, NI);

  // ---- final combine ----
  k_final<<<cdiv(NN * 64, 256), 256, 0, stream>>>(cgeb, msum, o2, o3, o4, o5, o0, o1);
}

// Round 4
// 2261.238 us; speedup vs baseline: 4.3533x; 1.2868x over previous
//
#include <hip/hip_runtime.h>
#include <stdint.h>

// ---------------- problem constants ----------------
#define NU 50000
#define NI 30000
#define NN 80000   // NU+NI
#define EK 64
#define HK 32
#define KV 4096
#define KT 384
#define NNZ_A 2000000
#define NNZ_R 1000000

#define JAX_PARTITIONABLE 1

// ---------------- threefry2x32 (20 rounds) ----------------
__host__ __device__ static inline void tf2x32(uint32_t k0, uint32_t k1,
                                              uint32_t x0, uint32_t x1,
                                              uint32_t& o0, uint32_t& o1) {
  uint32_t ks2 = k0 ^ k1 ^ 0x1BD11BDAu;
#define ROTL(x,d) (((x)<<(d))|((x)>>(32-(d))))
#define RND(r) { x0 += x1; x1 = ROTL(x1,r); x1 ^= x0; }
  x0 += k0; x1 += k1;
  RND(13) RND(15) RND(26) RND(6)
  x0 += k1;  x1 += ks2 + 1u;
  RND(17) RND(29) RND(16) RND(24)
  x0 += ks2; x1 += k0 + 2u;
  RND(13) RND(15) RND(26) RND(6)
  x0 += k0;  x1 += k1 + 3u;
  RND(17) RND(29) RND(16) RND(24)
  x0 += k1;  x1 += ks2 + 4u;
  RND(13) RND(15) RND(26) RND(6)
  x0 += ks2; x1 += k0 + 5u;
  o0 = x0; o1 = x1;
#undef RND
#undef ROTL
}

// ---------------- CSR build ----------------
__global__ void k_hist(const int* __restrict__ rows, int n, int* __restrict__ cnt) {
  int g = blockIdx.x * blockDim.x + threadIdx.x;
  if (g < n) atomicAdd(&cnt[rows[g]], 1);
}

__global__ void k_exscan(const int* __restrict__ cnt, int* __restrict__ ptr,
                         int* __restrict__ fill, int n) {
  __shared__ int wsum[16];
  __shared__ int s_carry;
  int tid = threadIdx.x;
  int lane = tid & 63, w = tid >> 6;
  if (tid == 0) s_carry = 0;
  __syncthreads();
  for (int base = 0; base < n; base += 1024) {
    int i = base + tid;
    int v = (i < n) ? cnt[i] : 0;
    int x = v;
    #pragma unroll
    for (int off = 1; off < 64; off <<= 1) {
      int y = __shfl_up(x, off, 64);
      if (lane >= off) x += y;
    }
    if (lane == 63) wsum[w] = x;
    __syncthreads();
    if (w == 0 && lane < 16) {
      int t = wsum[lane];
      #pragma unroll
      for (int off = 1; off < 16; off <<= 1) {
        int y = __shfl_up(t, off, 64);
        if (lane >= off) t += y;
      }
      wsum[lane] = t; // inclusive over wave sums
    }
    __syncthreads();
    int waveoff = (w == 0) ? 0 : wsum[w - 1];
    int excl = s_carry + waveoff + x - v;
    if (i < n) { ptr[i] = excl; fill[i] = excl; }
    __syncthreads();
    if (tid == 0) s_carry += wsum[15];
    __syncthreads();
  }
  if (tid == 0) ptr[n] = s_carry;
}

__global__ void k_scatter(const int* __restrict__ rows, const int* __restrict__ cols,
                          const float* __restrict__ vals, int n,
                          int* __restrict__ fill, int* __restrict__ ccol,
                          float* __restrict__ cval) {
  int g = blockIdx.x * blockDim.x + threadIdx.x;
  if (g >= n) return;
  int p = atomicAdd(&fill[rows[g]], 1);
  ccol[p] = cols[g];
  cval[p] = vals[g];
}

// ---------------- dense GEMM v4: P[split] = A(32-row tile x Kslice) @ B ----
// A: global->reg streamed with DEPTH-2 prefetch (3 live reg sets) -> ~1150cy of
// latency cover at 3 waves/SIMD. B: LDS double-buffered via global_load_lds,
// GBKC=32 so the barrier vmcnt-drain happens every 768 FMAs. ~100 VGPR, 24KB LDS.
#define GBM 32
#define GBKC 32
typedef const __attribute__((address_space(1))) void* as1cv;
typedef __attribute__((address_space(3))) void* as3v;

__global__ __launch_bounds__(128, 2)
void k_gemm96v4(const float* __restrict__ A, const float* __restrict__ B,
                float* __restrict__ P,    // partials: P + by*M*96
                int M, int K, int kchunk) {
  __shared__ __align__(16) float Bs[2][GBKC * 96];   // 2 x 12 KB
  const int tid  = threadIdx.x;
  const int tx   = tid & 15;        // 16 col-groups of 6
  const int ty   = tid >> 4;        // 8 row-groups of 4
  const int wv   = tid >> 6;        // wave 0..1
  const int lane = tid & 63;
  const int row0 = blockIdx.x * GBM;
  const int kbeg = blockIdx.y * kchunk;
  const int nchunk = kchunk / GBKC;     // kchunk multiple of GBKC

  const float* ap[4];
  #pragma unroll
  for (int i = 0; i < 4; ++i) {
    int gr = row0 + ty * 4 + i;
    if (gr > M - 1) gr = M - 1;       // clamp loads; stores guarded
    ap[i] = A + (size_t)gr * K + kbeg;
  }

  // prologue: stage chunk-0 B + A groups 0 and 1
  {
    const float* gB = B + (size_t)kbeg * 96;
    #pragma unroll
    for (int j = 0; j < 6; ++j) {
      int q0 = (wv * 6 + j) * 256;    // wave-uniform float index (1KB per DMA)
      __builtin_amdgcn_global_load_lds((as1cv)(gB + q0 + lane * 4),
                                       (as3v)(&Bs[0][q0]), 16, 0, 0);
    }
  }
  float4 a_cur[4], a_n1[4];
  #pragma unroll
  for (int i = 0; i < 4; ++i) a_cur[i] = *(const float4*)(ap[i]);
  #pragma unroll
  for (int i = 0; i < 4; ++i) a_n1[i] = *(const float4*)(ap[i] + 4);
  __syncthreads();                    // chunk0 + a_cur/a_n1 ready

  float acc[4][6] = {};
  for (int t = 0; t < nchunk; ++t) {
    if (t + 1 < nchunk) {             // next-chunk B DMA overlaps compute
      const float* gB = B + (size_t)(kbeg + (t + 1) * GBKC) * 96;
      float* bdst = Bs[(t + 1) & 1];
      #pragma unroll
      for (int j = 0; j < 6; ++j) {
        int q0 = (wv * 6 + j) * 256;
        __builtin_amdgcn_global_load_lds((as1cv)(gB + q0 + lane * 4),
                                         (as3v)(&bdst[q0]), 16, 0, 0);
      }
    }
    const float* bs = Bs[t & 1];
    #pragma unroll
    for (int k4 = 0; k4 < GBKC / 4; ++k4) {
      // issue loads for group (t,k4)+2; clamp at slice end (redundant ok)
      int kn = t * GBKC + k4 * 4 + 8;
      if (kn > kchunk - 4) kn = kchunk - 4;
      float4 a_nn[4];
      #pragma unroll
      for (int i = 0; i < 4; ++i) a_nn[i] = *(const float4*)(ap[i] + kn);
      #pragma unroll
      for (int kk = 0; kk < 4; ++kk) {
        const float* br = &bs[(k4 * 4 + kk) * 96 + tx * 6];
        float2 b0 = *(const float2*)(br);       // 16 distinct bank-pairs,
        float2 b1 = *(const float2*)(br + 2);   // 4-way ty broadcast: conflict-free
        float2 b2 = *(const float2*)(br + 4);
        float b[6] = {b0.x, b0.y, b1.x, b1.y, b2.x, b2.y};
        #pragma unroll
        for (int i = 0; i < 4; ++i) {
          float av = (kk == 0) ? a_cur[i].x : (kk == 1) ? a_cur[i].y
                   : (kk == 2) ? a_cur[i].z : a_cur[i].w;
          #pragma unroll
          for (int j = 0; j < 6; ++j) acc[i][j] += av * b[j];
        }
      }
      #pragma unroll
      for (int i = 0; i < 4; ++i) { a_cur[i] = a_n1[i]; a_n1[i] = a_nn[i]; }
    }
    __syncthreads();   // next B chunk landed; buf[t] free
  }

  float* pb = P + (size_t)blockIdx.y * M * 96;
  #pragma unroll
  for (int i = 0; i < 4; ++i) {
    int gr = row0 + ty * 4 + i;
    if (gr >= M) continue;
    float* pr = pb + (size_t)gr * 96 + tx * 6;
    #pragma unroll
    for (int j = 0; j < 6; ++j) pr[j] = acc[i][j];
  }
}

// reduce split-K partials: out cols 0..31 -> IH, 32..95 -> IF
__global__ void k_reduce_splits(const float* __restrict__ P, int nsplit, int M,
                                float* __restrict__ outIH, float* __restrict__ outIF) {
  int g = blockIdx.x * blockDim.x + threadIdx.x;
  if (g >= M * 96) return;
  float s = 0.0f;
  for (int sp = 0; sp < nsplit; ++sp) s += P[(size_t)sp * M * 96 + g];
  int r = g / 96, c = g - (g / 96) * 96;
  if (c < 32) outIH[(size_t)r * 32 + c] = s;
  else        outIF[(size_t)r * 64 + (c - 32)] = s;
}

// ---------------- sparse kernels (unroll-4 pipelined gathers) ----------------

// y(nrows x 64) = Aadj @ [xu; xi] (row r of source: r<split -> xu, else xi)
__global__ void k_spmm64s(const int* __restrict__ ptr, const int* __restrict__ col,
                          const float* __restrict__ val,
                          const float* __restrict__ xu, const float* __restrict__ xi,
                          int split, float* __restrict__ y, int nrows) {
  int g = blockIdx.x * blockDim.x + threadIdx.x;
  int row = g >> 6, lane = g & 63;
  if (row >= nrows) return;
  int jb = ptr[row], je = ptr[row + 1];
  float acc = 0.0f;
  int j = jb;
  for (; j + 3 < je; j += 4) {
    int c0 = col[j], c1 = col[j+1], c2 = col[j+2], c3 = col[j+3];
    float v0 = val[j], v1 = val[j+1], v2 = val[j+2], v3 = val[j+3];
    const float* p0 = (c0 < split) ? xu + (size_t)c0 * 64 : xi + (size_t)(c0 - split) * 64;
    const float* p1 = (c1 < split) ? xu + (size_t)c1 * 64 : xi + (size_t)(c1 - split) * 64;
    const float* p2 = (c2 < split) ? xu + (size_t)c2 * 64 : xi + (size_t)(c2 - split) * 64;
    const float* p3 = (c3 < split) ? xu + (size_t)c3 * 64 : xi + (size_t)(c3 - split) * 64;
    float y0 = p0[lane], y1 = p1[lane], y2 = p2[lane], y3 = p3[lane];
    acc += v0 * y0; acc += v1 * y1; acc += v2 * y2; acc += v3 * y3;
  }
  for (; j < je; ++j) {
    int c = col[j];
    const float* p = (c < split) ? xu + (size_t)c * 64 : xi + (size_t)(c - split) * 64;
    acc += val[j] * p[lane];
  }
  y[(size_t)row * 64 + lane] = acc;
}

// fused modality adj-pass: for both modalities, mge = Aadj @ [uf; itf],
// then msum = l2norm(mge_v) + l2norm(mge_t)  (written directly, no memset/RMW)
__global__ void k_mge(const int* __restrict__ ptr, const int* __restrict__ col,
                      const float* __restrict__ val,
                      const float* __restrict__ ufv, const float* __restrict__ itfv,
                      const float* __restrict__ uft, const float* __restrict__ itft,
                      float* __restrict__ msum, int nrows) {
  int g = blockIdx.x * blockDim.x + threadIdx.x;
  int row = g >> 6, lane = g & 63;
  if (row >= nrows) return;
  int jb = ptr[row], je = ptr[row + 1];
  float av = 0.0f, at = 0.0f;
  int j = jb;
  for (; j + 3 < je; j += 4) {
    int c0 = col[j], c1 = col[j+1], c2 = col[j+2], c3 = col[j+3];
    float v0 = val[j], v1 = val[j+1], v2 = val[j+2], v3 = val[j+3];
    const float* pv0 = (c0 < NU) ? ufv + (size_t)c0 * 64 : itfv + (size_t)(c0 - NU) * 64;
    const float* pt0 = (c0 < NU) ? uft + (size_t)c0 * 64 : itft + (size_t)(c0 - NU) * 64;
    const float* pv1 = (c1 < NU) ? ufv + (size_t)c1 * 64 : itfv + (size_t)(c1 - NU) * 64;
    const float* pt1 = (c1 < NU) ? uft + (size_t)c1 * 64 : itft + (size_t)(c1 - NU) * 64;
    const float* pv2 = (c2 < NU) ? ufv + (size_t)c2 * 64 : itfv + (size_t)(c2 - NU) * 64;
    const float* pt2 = (c2 < NU) ? uft + (size_t)c2 * 64 : itft + (size_t)(c2 - NU) * 64;
    const float* pv3 = (c3 < NU) ? ufv + (size_t)c3 * 64 : itfv + (size_t)(c3 - NU) * 64;
    const float* pt3 = (c3 < NU) ? uft + (size_t)c3 * 64 : itft + (size_t)(c3 - NU) * 64;
    float a0 = pv0[lane], b0 = pt0[lane], a1 = pv1[lane], b1 = pt1[lane];
    float a2 = pv2[lane], b2 = pt2[lane], a3 = pv3[lane], b3 = pt3[lane];
    av += v0 * a0; at += v0 * b0;
    av += v1 * a1; at += v1 * b1;
    av += v2 * a2; at += v2 * b2;
    av += v3 * a3; at += v3 * b3;
  }
  for (; j < je; ++j) {
    int c = col[j];
    float v = val[j];
    const float* pv = (c < NU) ? ufv + (size_t)c * 64 : itfv + (size_t)(c - NU) * 64;
    const float* pt = (c < NU) ? uft + (size_t)c * 64 : itft + (size_t)(c - NU) * 64;
    av += v * pv[lane]; at += v * pt[lane];
  }
  float sv = av * av, st = at * at;
  #pragma unroll
  for (int off = 32; off; off >>= 1) {
    sv += __shfl_xor(sv, off, 64);
    st += __shfl_xor(st, off, 64);
  }
  float iv = 1.0f / fmaxf(sqrtf(sv), 1e-12f);
  float it = 1.0f / fmaxf(sqrtf(st), 1e-12f);
  msum[(size_t)row * 64 + lane] = av * iv + at * it;
}

// fused R-pass pair: uf_m = (R @ itf_m) * inv_inters, m in {v,t}
__global__ void k_ruf(const int* __restrict__ ptr, const int* __restrict__ col,
                      const float* __restrict__ val,
                      const float* __restrict__ itfv, const float* __restrict__ itft,
                      const float* __restrict__ inv,
                      float* __restrict__ ufv, float* __restrict__ uft, int nrows) {
  int g = blockIdx.x * blockDim.x + threadIdx.x;
  int row = g >> 6, lane = g & 63;
  if (row >= nrows) return;
  int jb = ptr[row], je = ptr[row + 1];
  float av = 0.0f, at = 0.0f;
  int j = jb;
  for (; j + 3 < je; j += 4) {
    int c0 = col[j], c1 = col[j+1], c2 = col[j+2], c3 = col[j+3];
    float v0 = val[j], v1 = val[j+1], v2 = val[j+2], v3 = val[j+3];
    float a0 = itfv[(size_t)c0 * 64 + lane], b0 = itft[(size_t)c0 * 64 + lane];
    float a1 = itfv[(size_t)c1 * 64 + lane], b1 = itft[(size_t)c1 * 64 + lane];
    float a2 = itfv[(size_t)c2 * 64 + lane], b2 = itft[(size_t)c2 * 64 + lane];
    float a3 = itfv[(size_t)c3 * 64 + lane], b3 = itft[(size_t)c3 * 64 + lane];
    av += v0 * a0; at += v0 * b0;
    av += v1 * a1; at += v1 * b1;
    av += v2 * a2; at += v2 * b2;
    av += v3 * a3; at += v3 * b3;
  }
  for (; j < je; ++j) {
    int c = col[j];
    float v = val[j];
    av += v * itfv[(size_t)c * 64 + lane];
    at += v * itft[(size_t)c * 64 + lane];
  }
  float s = inv[row];
  ufv[(size_t)row * 64 + lane] = av * s;
  uft[(size_t)row * 64 + lane] = at * s;
}

// fused uh-logits pair: lanes 0..31 -> ihv, 32..63 -> iht (one wave per row)
__global__ void k_uh2(const int* __restrict__ ptr, const int* __restrict__ col,
                      const float* __restrict__ val,
                      const float* __restrict__ ihv, const float* __restrict__ iht,
                      float* __restrict__ uhv, float* __restrict__ uht, int nrows) {
  int g = blockIdx.x * blockDim.x + threadIdx.x;
  int row = g >> 6, lane = g & 63;
  if (row >= nrows) return;
  int c32 = lane & 31;
  const float* x = (lane < 32) ? ihv : iht;
  int jb = ptr[row], je = ptr[row + 1];
  float acc = 0.0f;
  int j = jb;
  for (; j + 3 < je; j += 4) {
    int c0 = col[j], c1 = col[j+1], c2 = col[j+2], c3 = col[j+3];
    float v0 = val[j], v1 = val[j+1], v2 = val[j+2], v3 = val[j+3];
    float y0 = x[(size_t)c0 * 32 + c32], y1 = x[(size_t)c1 * 32 + c32];
    float y2 = x[(size_t)c2 * 32 + c32], y3 = x[(size_t)c3 * 32 + c32];
    acc += v0 * y0; acc += v1 * y1; acc += v2 * y2; acc += v3 * y3;
  }
  for (; j < je; ++j) acc += val[j] * x[(size_t)col[j] * 32 + c32];
  float* yo = (lane < 32) ? uhv : uht;
  yo[(size_t)row * 32 + c32] = acc;
}

// ---------------- gumbel softmax (in-place over n x 32) ----------------
__global__ void k_gumbel_softmax(float* __restrict__ logits, int nrows,
                                 uint32_t k0, uint32_t k1) {
  int row = blockIdx.x * 8 + (threadIdx.x >> 5);
  int c = threadIdx.x & 31;
  if (row >= nrows) return;
  int e = row * 32 + c;
  uint32_t b0, b1, bits;
#if JAX_PARTITIONABLE
  tf2x32(k0, k1, 0u, (uint32_t)e, b0, b1);
  bits = b0 ^ b1;
#else
  int half = nrows * 16;
  if (e < half) { tf2x32(k0, k1, (uint32_t)e, (uint32_t)(e + half), b0, b1); bits = b0; }
  else          { tf2x32(k0, k1, (uint32_t)(e - half), (uint32_t)e, b0, b1); bits = b1; }
#endif
  const float TINY = 1.1754943508222875e-38f;
  float f = __uint_as_float((bits >> 9) | 0x3F800000u) - 1.0f;  // [0,1)
  float u = fmaxf(TINY, f + TINY);
  float g = -logf(-logf(u));
  float x = (logits[e] + g) / 0.2f;
  float m = x;
  #pragma unroll
  for (int off = 16; off; off >>= 1) m = fmaxf(m, __shfl_xor(m, off, 32));
  float ex = expf(x - m);
  float s = ex;
  #pragma unroll
  for (int off = 16; off; off >>= 1) s += __shfl_xor(s, off, 32);
  logits[e] = ex / s;
}

// ---------------- small utility kernels ----------------
// cge = ([Gu;Gi] + e1 + e2)/3  (no materialized ego)
__global__ void k_cge2(const float* __restrict__ Gu, const float* __restrict__ Gi,
                       const float* __restrict__ e1, const float* __restrict__ e2,
                       float* __restrict__ cge) {
  int g = blockIdx.x * blockDim.x + threadIdx.x;
  int row = g >> 6, lane = g & 63;
  if (row >= NN) return;
  size_t idx = (size_t)row * 64 + lane;
  float e0 = (row < NU) ? Gu[idx] : Gi[(size_t)(row - NU) * 64 + lane];
  cge[idx] = (e0 + e1[idx] + e2[idx]) / 3.0f;
}

// lat(32x64) += H(n x 32)^T @ X(n x 64)
__global__ void k_lat(const float* __restrict__ H, const float* __restrict__ X,
                      float* __restrict__ lat, int n) {
  int tid = threadIdx.x;
  int a = tid & 31, w = tid >> 5;        // w in 0..7 -> 8 cols each
  int i0 = blockIdx.x * 128;
  int iend = min(i0 + 128, n);
  float acc[8] = {};
  for (int i = i0; i < iend; ++i) {
    float h = H[(size_t)i * 32 + a];
    const float* xr = X + (size_t)i * 64 + w * 8;
    #pragma unroll
    for (int j = 0; j < 8; ++j) acc[j] += h * xr[j];
  }
  #pragma unroll
  for (int j = 0; j < 8; ++j) atomicAdd(&lat[a * 64 + w * 8 + j], acc[j]);
}

// out(n x 64) = H(n x 32) @ lat(32 x 64)
__global__ void k_hyper_out(const float* __restrict__ H, const float* __restrict__ lat,
                            float* __restrict__ out, int n) {
  __shared__ float ls[2048];
  int tid = threadIdx.x;
  for (int l = tid; l < 2048; l += 256) ls[l] = lat[l];
  __syncthreads();
  int row = blockIdx.x * 4 + (tid >> 6);
  int lane = tid & 63;
  if (row >= n) return;
  const float* h = H + (size_t)row * 32;
  float acc = 0.0f;
  #pragma unroll
  for (int a = 0; a < 32; ++a) acc += h[a] * ls[a * 64 + lane];
  out[(size_t)row * 64 + lane] = acc;
}

// B concat: bcat(K x 96) = [hyp(K x 32) | trs(K x 64)]
__global__ void k_concat_b(const float* __restrict__ hyp, const float* __restrict__ trs,
                           float* __restrict__ b, int K) {
  int g = blockIdx.x * blockDim.x + threadIdx.x;
  if (g >= K * 96) return;
  int k = g / 96, c = g % 96;
  b[g] = (c < 32) ? hyp[(size_t)k * 32 + c] : trs[(size_t)k * 64 + (c - 32)];
}

// final: lge = cge+msum; ghe from hyper outs; out = lge + 0.2*l2norm(ghe)
__global__ void k_final(const float* __restrict__ cge, const float* __restrict__ msum,
                        const float* __restrict__ o2, const float* __restrict__ o3,
                        const float* __restrict__ o4, const float* __restrict__ o5,
                        float* __restrict__ o0, float* __restrict__ o1) {
  int g = blockIdx.x * blockDim.x + threadIdx.x;
  int row = g >> 6, lane = g & 63;
  if (row >= NN) return;
  size_t idx = (size_t)row * 64 + lane;
  float lge = cge[idx] + msum[idx];
  float gv;
  size_t sub;
  if (row < NU) { sub = (size_t)row * 64 + lane;        gv = o2[sub] + o4[sub]; }
  else          { sub = (size_t)(row - NU) * 64 + lane; gv = o3[sub] + o5[sub]; }
  float s = gv * gv;
  #pragma unroll
  for (int off = 32; off; off >>= 1) s += __shfl_xor(s, off, 64);
  float inv = 1.0f / fmaxf(sqrtf(s), 1e-12f);
  float res = lge + 0.2f * gv * inv;
  if (row < NU) o0[sub] = res;
  else          o1[sub] = res;
}

static inline int cdiv(int a, int b) { return (a + b - 1) / b; }

extern "C" void kernel_launch(void* const* d_in, const int* in_sizes, int n_in,
                              void* d_out, int out_size, void* d_ws, size_t ws_size,
                              hipStream_t stream) {
  const float* Gu        = (const float*)d_in[0];
  const float* Gi        = (const float*)d_in[1];
  const float* feat_v    = (const float*)d_in[2];
  const float* feat_t    = (const float*)d_in[3];
  const float* trs_v     = (const float*)d_in[4];
  const float* trs_t     = (const float*)d_in[5];
  const float* hyp_v     = (const float*)d_in[6];
  const float* hyp_t     = (const float*)d_in[7];
  const float* inv_inters= (const float*)d_in[8];
  const float* adj_vals  = (const float*)d_in[9];
  const float* r_vals    = (const float*)d_in[10];
  const int*   adj_rows  = (const int*)d_in[11];
  const int*   adj_cols  = (const int*)d_in[12];
  const int*   r_rows    = (const int*)d_in[13];
  const int*   r_cols    = (const int*)d_in[14];

  float* W = (float*)d_ws;
  size_t off = 0;
  auto alloc = [&](size_t n) { float* p = W + off; off += (n + 63) & ~(size_t)63; return p; };
  int*   cntA  = (int*)alloc(NN);
  int*   ptrA  = (int*)alloc(NN + 1);
  int*   fillA = (int*)alloc(NN);
  int*   colA  = (int*)alloc(NNZ_A);
  float* valA  = alloc(NNZ_A);
  int*   cntR  = (int*)alloc(NU);
  int*   ptrR  = (int*)alloc(NU + 1);
  int*   fillR = (int*)alloc(NU);
  int*   colR  = (int*)alloc(NNZ_R);
  float* valR  = alloc(NNZ_R);
  float* bcv   = alloc((size_t)KV * 96);
  float* bct   = alloc((size_t)KT * 96);
  float* ihv   = alloc((size_t)NI * 32);
  float* iht   = alloc((size_t)NI * 32);
  float* itfv  = alloc((size_t)NI * 64);
  float* itft  = alloc((size_t)NI * 64);
  float* uhv   = alloc((size_t)NU * 32);
  float* uht   = alloc((size_t)NU * 32);
  float* ego   = alloc((size_t)NN * 64);   // used only as split-K partial space
  float* t1b   = alloc((size_t)NN * 64);   // UI temp, later uf_v
  float* t2b   = alloc((size_t)NN * 64);   // UI temp, later uf_t
  float* cgeb  = alloc((size_t)NN * 64);
  float* msum  = alloc((size_t)NN * 64);
  float* latv  = alloc(2048);
  float* latt  = alloc(2048);
  (void)ws_size; (void)in_sizes; (void)n_in; (void)out_size;

  // Split-K partial buffers ALIAS later-stage temporaries (contiguous region).
  // pv: 4*NI*96 = 11.52M floats fits in ego+t1b+t2b (15.36M). pt: 2*NI*96 =
  // 5.76M fits in cgeb+msum (10.24M). Reduces run before any later writes;
  // msum is fully written by k_mge (no memset), cgeb by k_cge2 — stream-ordered.
  float* pv = ego;
  float* pt = cgeb;

  float* o0 = (float*)d_out;
  float* o1 = o0 + (size_t)NU * 64;
  float* o2 = o1 + (size_t)NI * 64;
  float* o3 = o2 + (size_t)NU * 64;
  float* o4 = o3 + (size_t)NI * 64;
  float* o5 = o4 + (size_t)NU * 64;

  // ---- PRNG key derivation on host: key(42) -> fold_in(m) -> split ----
  uint32_t ks[2][4];
  for (int m = 0; m < 2; ++m) {
    uint32_t a, b;
    tf2x32(0u, 42u, 0u, (uint32_t)m, a, b);
#if JAX_PARTITIONABLE
    uint32_t p0, p1, q0, q1;
    tf2x32(a, b, 0u, 0u, p0, p1);   // k1
    tf2x32(a, b, 0u, 1u, q0, q1);   // k2
    ks[m][0] = p0; ks[m][1] = p1; ks[m][2] = q0; ks[m][3] = q1;
#else
    uint32_t p0, p1, q0, q1;
    tf2x32(a, b, 0u, 2u, p0, p1);
    tf2x32(a, b, 1u, 3u, q0, q1);
    ks[m][0] = p0; ks[m][1] = q0; ks[m][2] = p1; ks[m][3] = q1;
#endif
  }

  // ---- zero init ----
  hipMemsetAsync(cntA, 0, (size_t)NN * 4, stream);
  hipMemsetAsync(cntR, 0, (size_t)NU * 4, stream);
  hipMemsetAsync(latv, 0, 2048 * 4, stream);
  hipMemsetAsync(latt, 0, 2048 * 4, stream);

  // ---- CSR build for adj and R ----
  k_hist<<<cdiv(NNZ_A, 256), 256, 0, stream>>>(adj_rows, NNZ_A, cntA);
  k_hist<<<cdiv(NNZ_R, 256), 256, 0, stream>>>(r_rows, NNZ_R, cntR);
  k_exscan<<<1, 1024, 0, stream>>>(cntA, ptrA, fillA, NN);
  k_exscan<<<1, 1024, 0, stream>>>(cntR, ptrR, fillR, NU);
  k_scatter<<<cdiv(NNZ_A, 256), 256, 0, stream>>>(adj_rows, adj_cols, adj_vals, NNZ_A, fillA, colA, valA);
  k_scatter<<<cdiv(NNZ_R, 256), 256, 0, stream>>>(r_rows, r_cols, r_vals, NNZ_R, fillR, colR, valR);

  // ---- dense GEMMs: [ih_logits | item_feats] = feat @ [hyp | trs] ----
  k_concat_b<<<cdiv(KV * 96, 256), 256, 0, stream>>>(hyp_v, trs_v, bcv, KV);
  k_concat_b<<<cdiv(KT * 96, 256), 256, 0, stream>>>(hyp_t, trs_t, bct, KT);
  {
    dim3 gv(cdiv(NI, GBM), 4);   // kchunk 1024 = 32 chunks of 32
    k_gemm96v4<<<gv, 128, 0, stream>>>(feat_v, bcv, pv, NI, KV, 1024);
    dim3 gt(cdiv(NI, GBM), 2);   // kchunk 192 = 6 chunks of 32
    k_gemm96v4<<<gt, 128, 0, stream>>>(feat_t, bct, pt, NI, KT, 192);
    k_reduce_splits<<<cdiv(NI * 96, 256), 256, 0, stream>>>(pv, 4, NI, ihv, itfv);
    k_reduce_splits<<<cdiv(NI * 96, 256), 256, 0, stream>>>(pt, 2, NI, iht, itft);
  }

  // ---- uh_logits = R @ ih_logits (before softmax!), fused pair ----
  k_uh2<<<cdiv(NU * 64, 256), 256, 0, stream>>>(ptrR, colR, valR, ihv, iht, uhv, uht, NU);

  // ---- gumbel softmax in place ----
  k_gumbel_softmax<<<cdiv(NI, 8), 256, 0, stream>>>(ihv, NI, ks[0][0], ks[0][1]);
  k_gumbel_softmax<<<cdiv(NU, 8), 256, 0, stream>>>(uhv, NU, ks[0][2], ks[0][3]);
  k_gumbel_softmax<<<cdiv(NI, 8), 256, 0, stream>>>(iht, NI, ks[1][0], ks[1][1]);
  k_gumbel_softmax<<<cdiv(NU, 8), 256, 0, stream>>>(uht, NU, ks[1][2], ks[1][3]);

  // ---- UI propagation (no ego materialization): cge = (e0 + e1 + e2)/3 ----
  k_spmm64s<<<cdiv(NN * 64, 256), 256, 0, stream>>>(ptrA, colA, valA, Gu, Gi, NU, t1b, NN);
  k_spmm64s<<<cdiv(NN * 64, 256), 256, 0, stream>>>(ptrA, colA, valA, t1b, t1b, NN, t2b, NN);
  k_cge2<<<cdiv(NN * 64, 256), 256, 0, stream>>>(Gu, Gi, t1b, t2b, cgeb);

  // ---- modality graph embeddings, fully fused (t1b=uf_v, t2b=uf_t) ----
  k_ruf<<<cdiv(NU * 64, 256), 256, 0, stream>>>(ptrR, colR, valR, itfv, itft, inv_inters, t1b, t2b, NU);
  k_mge<<<cdiv(NN * 64, 256), 256, 0, stream>>>(ptrA, colA, valA, t1b, itfv, t2b, itft, msum, NN);

  // ---- hypergraph pass: lat = ih^T @ item_cge; u_ret = uh@lat; i_ret = ih@lat ----
  const float* item_cge = cgeb + (size_t)NU * 64;
  k_lat<<<cdiv(NI, 128), 256, 0, stream>>>(ihv, item_cge, latv, NI);
  k_hyper_out<<<cdiv(NU, 4), 256, 0, stream>>>(uhv, latv, o2, NU);
  k_hyper_out<<<cdiv(NI, 4), 256, 0, stream>>>(ihv, latv, o3, NI);
  k_lat<<<cdiv(NI, 128), 256, 0, stream>>>(iht, item_cge, latt, NI);
  k_hyper_out<<<cdiv(NU, 4), 256, 0, stream>>>(uht, latt, o4, NU);
  k_hyper_out<<<cdiv(NI, 4), 256, 0, stream>>>(iht, latt, o5, NI);

  // ---- final combine ----
  k_final<<<cdiv(NN * 64, 256), 256, 0, stream>>>(cgeb, msum, o2, o3, o4, o5, o0, o1);
}